// Round 3
// baseline (26.291 us; speedup 1.0000x reference)
//
#include <hip/hip_runtime.h>

#define BB 8
#define SS 4096
#define DD 64
#define NH 8
#define NBKT 64
#define OUT_V_ELEMS (BB*SS*DD)   // 2097152 floats of o, then buckets (BB*NH*SS floats)

// Grid: 1024 blocks = B(8) * hash-quad(2) * token-chunk(64).  Block: 256 thr = 4 waves.
// Wave w handles hash h = hq*4 + w over the block's 64 tokens; lane = token.
// qk tile staged in LDS [64 tok][64 f] with per-row float4-group XOR swizzle.
// rot rows read via wave-uniform (scalar) loads -> SGPRs; FMA reads 1 SGPR/instr.
__global__ __launch_bounds__(256) void lsh_hash_kernel(
    const float* __restrict__ qk,
    const float* __restrict__ v,
    const float* __restrict__ rot,
    float* __restrict__ out)
{
    __shared__ float qk_s[64 * 64];   // 16 KB

    const int tid = threadIdx.x;
    const int blk = blockIdx.x;
    const int b   = blk >> 7;        // 0..7
    const int r   = blk & 127;
    const int hq  = r >> 6;          // 0..1
    const int tc  = r & 63;          // 0..63
    const int t0  = tc * 64;

    // ---- fused v -> out[0] copy (output 0 == v exactly; self-mask keeps only t==t slots) ----
    // v is 2M floats = 524288 float4; 1024 blocks * 512 float4 each.
    {
        const float4* v4 = (const float4*)v;
        float4*       o4 = (float4*)out;
        const int base = blk * 512 + tid;
        o4[base]       = v4[base];
        o4[base + 256] = v4[base + 256];
    }

    // ---- stage qk tile: qk_s[tok*64 + (g ^ (tok&15))*4 ..] = qk[b, t0+tok, g*4..] ----
    {
        const float4* qg = (const float4*)qk;
#pragma unroll
        for (int k = 0; k < 4; ++k) {
            const int p   = tid + k * 256;   // 1024 float4s
            const int tok = p >> 4, g = p & 15;
            const float4 x = qg[(b * SS + t0 + tok) * 16 + g];
            *(float4*)&qk_s[tok * 64 + ((g ^ (tok & 15)) << 2)] = x;
        }
    }
    __syncthreads();

    // ---- per-wave hash, per-lane token, all 32 candidate dirs in registers ----
    const int lane = tid & 63;
    const int h    = hq * 4 + (tid >> 6);
    const int h_u  = __builtin_amdgcn_readfirstlane(h);
    const float* __restrict__ rot_h = rot + h_u * 32;   // rot[f*256 + h*32 + i]

    float acc[32];
#pragma unroll
    for (int i = 0; i < 32; ++i) acc[i] = 0.0f;

    const int lrow = lane * 64;
    const int lsw  = lane & 15;

#pragma unroll
    for (int fg = 0; fg < 16; ++fg) {
        const float4 q4 = *(const float4*)&qk_s[lrow + ((fg ^ lsw) << 2)];
        const float qa[4] = {q4.x, q4.y, q4.z, q4.w};
#pragma unroll
        for (int j = 0; j < 4; ++j) {
            const float* __restrict__ rp = rot_h + (fg * 4 + j) * (NH * 32);
            float rr[32];
#pragma unroll
            for (int i = 0; i < 32; ++i) rr[i] = rp[i];   // wave-uniform -> s_load
            const float qf = qa[j];
#pragma unroll
            for (int i = 0; i < 32; ++i)
                acc[i] = fmaf(qf, rr[i], acc[i]);
        }
    }

    // ---- argmax over concat([r, -r]), first-occurrence tie-break, positive half wins ties ----
    float pv = acc[0]; int pi = 0;
    float nv = -acc[0]; int ni = 0;
#pragma unroll
    for (int i = 1; i < 32; ++i) {
        if (acc[i]  > pv) { pv = acc[i];  pi = i; }
        if (-acc[i] > nv) { nv = -acc[i]; ni = i; }
    }
    const int idx = (pv >= nv) ? pi : (ni + 32);
    out[OUT_V_ELEMS + b * (NH * SS) + h * SS + t0 + lane] = (float)(idx + h * NBKT);
}

extern "C" void kernel_launch(void* const* d_in, const int* in_sizes, int n_in,
                              void* d_out, int out_size, void* d_ws, size_t ws_size,
                              hipStream_t stream) {
    const float* qk  = (const float*)d_in[0];
    const float* v   = (const float*)d_in[1];
    const float* rot = (const float*)d_in[2];
    float* out = (float*)d_out;
    hipLaunchKernelGGL(lsh_hash_kernel, dim3(1024), dim3(256), 0, stream,
                       qk, v, rot, out);
}

// Round 5
// 25.199 us; speedup vs baseline: 1.0433x; 1.0433x over previous
//
#include <hip/hip_runtime.h>

#define BB 8
#define SS 4096
#define DD 64
#define NH 8
#define NBKT 64
#define OUT_V_ELEMS (BB*SS*DD)   // 2097152 floats of o, then buckets (BB*NH*SS floats)

// Grid: 512 blocks = b(8) * hq(2) * chunk(32 of 128 tokens). Block: 128 thr = 2 waves.
// Wave wv: tokens t0 + wv*64 + tx*8 .. +7 (tx = lane&7); ty = lane>>3 picks 16 of the
// hash-quad's 128 dirs (hash_local = ty>>1, dir-half = ty&1). Thread tile:
// 8 tokens x 16 dirs = 128 acc. Per f: 24 LDS floats / 128 FMAs = 0.75 B/FMA.
__global__ __launch_bounds__(128) void lsh_hash_kernel(
    const float* __restrict__ qk,
    const float* __restrict__ v,
    const float* __restrict__ rot,
    float* __restrict__ out)
{
    __shared__ float q_s[128 * 64];    // [tok][f], f-chunk XOR swizzle: chunk' = fc ^ ((tok>>3)&7)
    __shared__ float rot_s[64 * 128];  // [f][slot*4], slot(c) = (c&3)*8 + (c>>2), c = quad dir-chunk

    const int tid = threadIdx.x;
    const int blk = blockIdx.x;
    const int b   = blk >> 6;          // 0..7
    const int hq  = (blk >> 5) & 1;    // 0..1
    const int ch  = blk & 31;          // 0..31
    const int t0  = ch * 128;

    // ---- fused v -> out[0] copy (output 0 == v exactly; self-mask keeps only t==t slots) ----
    // v = 524288 float4 = 512 blocks * 1024; 128 threads * 8 each.
    {
        const float4* v4 = (const float4*)v;
        float4*       o4 = (float4*)out;
        const int base = blk * 1024 + tid;
#pragma unroll
        for (int j = 0; j < 8; ++j)
            o4[base + j * 128] = v4[base + j * 128];
    }

    // ---- stage qk tile: 128 tok x 16 f-chunks ----
    {
        const float4* qg = (const float4*)qk;
#pragma unroll
        for (int k = 0; k < 16; ++k) {
            const int p   = k * 128 + tid;       // 2048 float4
            const int tok = p >> 4, fc = p & 15;
            const float4 x = qg[(b * SS + t0 + tok) * 16 + fc];
            *(float4*)&q_s[tok * 64 + ((fc ^ ((tok >> 3) & 7)) << 2)] = x;
        }
    }
    // ---- stage rot quad: 64 f x 32 dir-chunks, permuted slots ----
    {
        const float4* rg = (const float4*)rot;
#pragma unroll
        for (int k = 0; k < 16; ++k) {
            const int p = k * 128 + tid;         // 2048 float4
            const int f = p >> 5, c = p & 31;
            const float4 x = rg[f * 64 + hq * 32 + c];
            const int slot = (c & 3) * 8 + (c >> 2);
            *(float4*)&rot_s[f * 128 + slot * 4] = x;
        }
    }
    __syncthreads();

    const int lane = tid & 63;
    const int wv   = tid >> 6;          // wave: token offset wv*64
    const int tx   = lane & 7;
    const int ty   = lane >> 3;
    const int trow = (wv * 64 + tx * 8) * 64;    // float base of first owned token row
    const int rbase = ty * 4;                    // float offset of slot ty within a p-group

    float acc[8][16];
#pragma unroll
    for (int a = 0; a < 8; ++a)
#pragma unroll
        for (int c = 0; c < 16; ++c) acc[a][c] = 0.0f;

    float4 qA[8], qB[8];
#define LOADQ(dst, fq_)                                                    \
    {                                                                      \
        const int qc = (((fq_) ^ tx) << 2);                                \
        _Pragma("unroll")                                                  \
        for (int a = 0; a < 8; ++a)                                        \
            dst[a] = *(const float4*)&q_s[trow + a * 64 + qc];             \
    }
    // thread ty wants quad dir-chunks ty*4+p (p=0..3), stored at slot p*8+ty,
    // i.e. float offset p*32 + ty*4.  (round-4 bug: had p*8 + ty*4)
#define COMPUTE(qr, fq_)                                                   \
    {                                                                      \
        _Pragma("unroll")                                                  \
        for (int df = 0; df < 4; ++df) {                                   \
            const int f = (fq_) * 4 + df;                                  \
            float4 r4[4];                                                  \
            _Pragma("unroll")                                              \
            for (int p = 0; p < 4; ++p)                                    \
                r4[p] = *(const float4*)&rot_s[f * 128 + p * 32 + rbase];  \
            const float rr[16] = {r4[0].x, r4[0].y, r4[0].z, r4[0].w,      \
                                  r4[1].x, r4[1].y, r4[1].z, r4[1].w,      \
                                  r4[2].x, r4[2].y, r4[2].z, r4[2].w,      \
                                  r4[3].x, r4[3].y, r4[3].z, r4[3].w};     \
            _Pragma("unroll")                                              \
            for (int a = 0; a < 8; ++a) {                                  \
                const float qf = df == 0 ? qr[a].x : df == 1 ? qr[a].y     \
                                 : df == 2 ? qr[a].z : qr[a].w;            \
                _Pragma("unroll")                                          \
                for (int c = 0; c < 16; ++c)                               \
                    acc[a][c] = fmaf(qf, rr[c], acc[a][c]);                \
            }                                                              \
        }                                                                  \
    }

    LOADQ(qA, 0);
#pragma unroll 1
    for (int fq = 0; fq < 16; fq += 2) {
        LOADQ(qB, fq + 1);
        COMPUTE(qA, fq);
        if (fq + 2 < 16) LOADQ(qA, fq + 2);
        COMPUTE(qB, fq + 1);
    }

    // ---- argmax over concat([r, -r]) with reference tie-breaks ----
    const int h     = hq * 4 + (ty >> 1);
    const int dbase = (ty & 1) * 16;    // dir offset within the hash
    float* bout = out + OUT_V_ELEMS + b * (NH * SS) + h * SS + t0 + wv * 64 + tx * 8;

#pragma unroll
    for (int a = 0; a < 8; ++a) {
        float pv = acc[a][0]; int pi = dbase;
        float nv = -acc[a][0]; int ni = dbase;
#pragma unroll
        for (int c = 1; c < 16; ++c) {
            const float x = acc[a][c];
            if (x  > pv) { pv = x;  pi = dbase + c; }   // strict > = first occurrence
            if (-x > nv) { nv = -x; ni = dbase + c; }
        }
        // merge with the partner lane (lane^8) holding the other dir-half of this hash
        const float opv = __shfl_xor(pv, 8);
        const int   opi = __shfl_xor(pi, 8);
        const float onv = __shfl_xor(nv, 8);
        const int   oni = __shfl_xor(ni, 8);
        if (opv > pv || (opv == pv && opi < pi)) { pv = opv; pi = opi; }
        if (onv > nv || (onv == nv && oni < ni)) { nv = onv; ni = oni; }
        const int idx = (pv >= nv) ? pi : (ni + 32);    // positive half wins ties
        if ((ty & 1) == 0) bout[a] = (float)(idx + h * NBKT);
    }
#undef LOADQ
#undef COMPUTE
}

extern "C" void kernel_launch(void* const* d_in, const int* in_sizes, int n_in,
                              void* d_out, int out_size, void* d_ws, size_t ws_size,
                              hipStream_t stream) {
    const float* qk  = (const float*)d_in[0];
    const float* v   = (const float*)d_in[1];
    const float* rot = (const float*)d_in[2];
    float* out = (float*)d_out;
    hipLaunchKernelGGL(lsh_hash_kernel, dim3(512), dim3(128), 0, stream,
                       qk, v, rot, out);
}